// Round 8
// baseline (227.285 us; speedup 1.0000x reference)
//
#include <hip/hip_runtime.h>
#include <hip/hip_bf16.h>
#include <hip/hip_fp16.h>
#include <stdint.h>

#define H 256
#define BT 4096
#define TS 128
#define ROWS 16
#define NBLK 256   // BT/ROWS, 1 block per CU
#define NTH 1024   // 16 waves: 8 GEMM + 8 LN, 4/SIMD
#define LD 260     // emb row (floats)
#define LDP 264    // hp row (u32, 2-row packed f16)

typedef __attribute__((ext_vector_type(8))) _Float16 f16x8;
typedef __attribute__((ext_vector_type(4))) float f32x4;

__device__ __forceinline__ float exp2_fast(float x){ float r; asm("v_exp_f32 %0, %1" : "=v"(r) : "v"(x)); return r; }
__device__ __forceinline__ float rcp_fast(float x){ float r; asm("v_rcp_f32 %0, %1" : "=v"(r) : "v"(x)); return r; }
__device__ __forceinline__ float rsq_fast(float x){ float r; asm("v_rsq_f32 %0, %1" : "=v"(r) : "v"(x)); return r; }
__device__ __forceinline__ float tanh_fast(float x){
  float e = exp2_fast(x * 2.8853900817779268f);
  return 1.0f - 2.0f * rcp_fast(e + 1.0f);
}
__device__ __forceinline__ unsigned pk_f16(float a, float b){
  __half2 h2 = __float22half2_rn(make_float2(a, b));   // a in low 16
  union { __half2 h; unsigned u; } cv; cv.h = h2; return cv.u;
}
__device__ __forceinline__ float f16_lo(unsigned v){   // cvt low 16 f16->f32
  float r; asm("v_cvt_f32_f16 %0, %1" : "=v"(r) : "v"(v)); return r;
}
__device__ __forceinline__ unsigned pk_bf16(float a, float b){
  __hip_bfloat162 h2 = __float22bfloat162_rn(make_float2(a, b));
  union { __hip_bfloat162 h; unsigned u; } cv; cv.h = h2; return cv.u;
}
// barrier w/o vmcnt drain: cross-wave deps are LDS-only; hist ld/st same-wave, 61+ steps apart
__device__ __forceinline__ void bar_lgkm(){ asm volatile("s_waitcnt lgkmcnt(0)\n\ts_barrier" ::: "memory"); }

template<int CTRL>
__device__ __forceinline__ float dpp_add(float x){
  int y = __builtin_amdgcn_update_dpp(0, __float_as_int(x), CTRL, 0xf, 0xf, false);
  return x + __int_as_float(y);
}
#define ROR1 0x121
#define ROR2 0x122
#define ROR4 0x124
#define ROR8 0x128
#define BC15 0x142
#define BC31 0x143
__device__ __forceinline__ float lane_f(float v, int n){
  return __int_as_float(__builtin_amdgcn_readlane(__float_as_int(v), n));
}
#define CHAIN(s) do { \
    s = dpp_add<ROR1>(s); s = dpp_add<ROR2>(s); s = dpp_add<ROR4>(s); s = dpp_add<ROR8>(s); \
    s = dpp_add<BC15>(s); s = dpp_add<BC31>(s); } while(0)

__global__ __launch_bounds__(NTH, 4) void wp_kernel(
    const float* __restrict__ x, const float* __restrict__ We, const float* __restrict__ be,
    const float* __restrict__ Wu, const float* __restrict__ bu, const float* __restrict__ gm,
    const float* __restrict__ bt, const float* __restrict__ Wo, const float* __restrict__ bo,
    const float* __restrict__ cst, unsigned short* __restrict__ hist, float* __restrict__ out,
    int use_hist)
{
  __shared__ __align__(16) float emb[10][LD];
  // h-pre-LN, f16 2-row packed: hp[rp][c] = (h[2rp][c] lo16, h[2rp+1][c] hi16)
  __shared__ __align__(16) unsigned hp[8][LDP];
  __shared__ __align__(16) float hfin[ROWS][LDP];   // final f32 h (t=127 only)
  // A frags (f16): element k=32kc+8fo'+4e'+j of row r in plane kc, physical row
  // (r+16fo')^kc^(2fo'). b128 reads + b64 writes conflict-free (HW-verified r4-r7: 0 conflicts)
  __shared__ __align__(16) unsigned short afrag[8][64][8];
  __shared__ unsigned char xidx[ROWS][TS];

  const int tid = threadIdx.x;
  const int r0 = blockIdx.x * ROWS;
  const int w  = tid >> 6;
  const int l  = tid & 63;
  const int fr = l & 15;
  const int fo = l >> 4;
  const bool isG = (w < 8);       // GEMM wave: cols [32w, 32w+32)
  const int  li  = w & 7;         // LN wave index: rows 2li, 2li+1

  float cs;
  { float c = cst[0]; cs = rcp_fast(1.0f + exp2_fast(-c * 1.4426950408889634f)); }

  for (int i = tid; i < ROWS*TS; i += NTH) {
    int r = i >> 7, t = i & 127;
    xidx[r][t] = (unsigned char)(int)(x[((size_t)(r0 + r))*TS + t] + 0.5f);
  }
  for (int i = tid; i < 10*H; i += NTH) {
    int v = i >> 8, k = i & 255;
    emb[v][k] = tanh_fast((float)v * We[k] + be[k]);
  }

  // ---- G-wave state: W_update f16 frags for 32 cols (64 regs), biases ----
  const int c0 = 32*li + fr, c1 = c0 + 16;
  f16x8 wf0[8], wf1[8];
  float bval0 = 0.f, bval1 = 0.f;
  if (isG) {
    #pragma unroll
    for (int kc = 0; kc < 8; ++kc) {
      #pragma unroll
      for (int i = 0; i < 8; ++i) {
        int kg = 32*kc + 8*fo + i;
        wf0[kc][i] = (_Float16)Wu[(size_t)kg*H + c0];
        wf1[kc][i] = (_Float16)Wu[(size_t)kg*H + c1];
      }
    }
    bval0 = bu[c0]; bval1 = bu[c1];
  }

  // ---- L-wave state ----
  const int re = 2*li, ro = re + 1;
  f32x4 g4 = {0,0,0,0}, b4 = {0,0,0,0};
  if (!isG) {
    g4 = *(const f32x4*)(gm + 4*l);
    b4 = *(const f32x4*)(bt + 4*l);
  }
  const int wkc = l >> 3, wfo = (l >> 1) & 3, we = l & 1;
  unsigned short* const awE = &afrag[wkc][(re + 16*wfo) ^ wkc ^ (2*wfo)][4*we];
  unsigned short* const awO = &afrag[wkc][(ro + 16*wfo) ^ wkc ^ (2*wfo)][4*we];
  const unsigned* const hpr = &hp[li][4*l];
  const unsigned char* const xrE = &xidx[re][0];
  const unsigned char* const xrO = &xidx[ro][0];
  const size_t histLaneE = (size_t)(r0 + re)*H + 4*l;
  const size_t histLaneO = (size_t)(r0 + ro)*H + 4*l;
  const int XR = l ^ (2*fo);      // phase2 afrag read row base (^kc per plane)
  __syncthreads();

  // prologue: A-frags for t=0 (h=0, no ctx), built by L waves
  if (!isG) {
    int xv = xrE[0];
    f32x4 e4 = *(const f32x4*)&emb[xv][4*l];
    uint2 p = { pk_f16(e4[0], e4[1]), pk_f16(e4[2], e4[3]) };
    *(uint2*)awE = p;
    xv = xrO[0];
    e4 = *(const f32x4*)&emb[xv][4*l];
    uint2 q = { pk_f16(e4[0], e4[1]), pk_f16(e4[2], e4[3]) };
    *(uint2*)awO = q;
  }
  __syncthreads();

  uint2 cPe = {0,0}, cQe = {0,0}, cPo = {0,0}, cQo = {0,0};

// phase 2 (G waves): h_pre = tanh(A @ Wu + bu) for 32 cols; bias pre-seeded in acc
#define PHASE2() do { \
    f32x4 acc0 = {bval0, bval0, bval0, bval0}; \
    f32x4 acc1 = {bval1, bval1, bval1, bval1}; \
    _Pragma("unroll") \
    for (int kc = 0; kc < 8; ++kc) { \
      f16x8 af = *(const f16x8*)&afrag[kc][XR ^ kc][0]; \
      acc0 = __builtin_amdgcn_mfma_f32_16x16x32_f16(af, wf0[kc], acc0, 0, 0, 0); \
      acc1 = __builtin_amdgcn_mfma_f32_16x16x32_f16(af, wf1[kc], acc1, 0, 0, 0); \
    } \
    hp[2*fo  ][c0] = pk_f16(tanh_fast(acc0[0]), tanh_fast(acc0[1])); \
    hp[2*fo+1][c0] = pk_f16(tanh_fast(acc0[2]), tanh_fast(acc0[3])); \
    hp[2*fo  ][c1] = pk_f16(tanh_fast(acc1[0]), tanh_fast(acc1[1])); \
    hp[2*fo+1][c1] = pk_f16(tanh_fast(acc1[2]), tanh_fast(acc1[3])); \
  } while(0)

// LN for the wave's two packed rows; leaves hve0..3 / hvo0..3 defined
#define LN2() \
    uint4 qv = *(const uint4*)hpr; \
    float he0 = f16_lo(qv.x),       he1 = f16_lo(qv.y),       he2 = f16_lo(qv.z),       he3 = f16_lo(qv.w); \
    float ho0 = f16_lo(qv.x >> 16), ho1 = f16_lo(qv.y >> 16), ho2 = f16_lo(qv.z >> 16), ho3 = f16_lo(qv.w >> 16); \
    float s1e = (he0+he1) + (he2+he3); \
    float s2e = he0*he0; s2e = fmaf(he1,he1,s2e); s2e = fmaf(he2,he2,s2e); s2e = fmaf(he3,he3,s2e); \
    float s1o = (ho0+ho1) + (ho2+ho3); \
    float s2o = ho0*ho0; s2o = fmaf(ho1,ho1,s2o); s2o = fmaf(ho2,ho2,s2o); s2o = fmaf(ho3,ho3,s2o); \
    CHAIN(s1e); CHAIN(s2e); CHAIN(s1o); CHAIN(s2o); \
    float mue  = lane_f(s1e,63) * 0.00390625f; \
    float vare = lane_f(s2e,63) * 0.00390625f - mue*mue; \
    float rse  = rsq_fast(vare + 1e-5f); \
    float muo  = lane_f(s1o,63) * 0.00390625f; \
    float varo = lane_f(s2o,63) * 0.00390625f - muo*muo; \
    float rso  = rsq_fast(varo + 1e-5f); \
    float hve0 = fmaf(he0-mue, rse*g4[0], b4[0]); \
    float hve1 = fmaf(he1-mue, rse*g4[1], b4[1]); \
    float hve2 = fmaf(he2-mue, rse*g4[2], b4[2]); \
    float hve3 = fmaf(he3-mue, rse*g4[3], b4[3]); \
    float hvo0 = fmaf(ho0-muo, rso*g4[0], b4[0]); \
    float hvo1 = fmaf(ho1-muo, rso*g4[1], b4[1]); \
    float hvo2 = fmaf(ho2-muo, rso*g4[2], b4[2]); \
    float hvo3 = fmaf(ho3-muo, rso*g4[3], b4[3]);

// phase 3 (L waves): LN + next A-frags + hist I/O for rows re, ro
#define PHASE3(HW, CUSE, CLOAD, tt) do { \
    int xve = xrE[(tt)+1], xvo = xrO[(tt)+1]; \
    f32x4 ee = *(const f32x4*)&emb[xve][4*l]; \
    f32x4 eo = *(const f32x4*)&emb[xvo][4*l]; \
    LN2(); \
    float a0, a1, a2, a3, d0, d1, d2, d3; \
    if ((CUSE) && use_hist) { \
      a0 = fmaf(cs, __uint_as_float(cPe.x << 16),         ee[0] + hve0); \
      a1 = fmaf(cs, __uint_as_float(cPe.x & 0xffff0000u), ee[1] + hve1); \
      a2 = fmaf(cs, __uint_as_float(cPe.y << 16),         ee[2] + hve2); \
      a3 = fmaf(cs, __uint_as_float(cPe.y & 0xffff0000u), ee[3] + hve3); \
      d0 = fmaf(cs, __uint_as_float(cPo.x << 16),         eo[0] + hvo0); \
      d1 = fmaf(cs, __uint_as_float(cPo.x & 0xffff0000u), eo[1] + hvo1); \
      d2 = fmaf(cs, __uint_as_float(cPo.y << 16),         eo[2] + hvo2); \
      d3 = fmaf(cs, __uint_as_float(cPo.y & 0xffff0000u), eo[3] + hvo3); \
    } else { \
      a0 = ee[0] + hve0; a1 = ee[1] + hve1; a2 = ee[2] + hve2; a3 = ee[3] + hve3; \
      d0 = eo[0] + hvo0; d1 = eo[1] + hvo1; d2 = eo[2] + hvo2; d3 = eo[3] + hvo3; \
    } \
    uint2 pe = { pk_f16(a0,a1), pk_f16(a2,a3) }; \
    *(uint2*)awE = pe; \
    uint2 po = { pk_f16(d0,d1), pk_f16(d2,d3) }; \
    *(uint2*)awO = po; \
    if ((HW) && use_hist) { \
      uint2 hbe = { pk_bf16(hve0,hve1), pk_bf16(hve2,hve3) }; \
      *(uint2*)(hist + (size_t)(tt)*(BT*H) + histLaneE) = hbe; \
      uint2 hbo = { pk_bf16(hvo0,hvo1), pk_bf16(hvo2,hvo3) }; \
      *(uint2*)(hist + (size_t)(tt)*(BT*H) + histLaneO) = hbo; \
    } \
    if ((CUSE) || (CLOAD)) { cPe = cQe; cPo = cQo; } \
    if ((CLOAD) && use_hist) { \
      cQe = *(const uint2*)(hist + (size_t)((tt)-61)*(BT*H) + histLaneE); \
      cQo = *(const uint2*)(hist + (size_t)((tt)-61)*(BT*H) + histLaneO); \
    } \
  } while(0)

#define STEP(HW, CUSE, CLOAD, tt) do { \
    if (isG) PHASE2(); \
    bar_lgkm(); \
    if (!isG) PHASE3(HW, CUSE, CLOAD, tt); \
    bar_lgkm(); \
  } while(0)

  // segmented t-loop: step-uniform branches resolved at compile time per segment
  for (int t = 0; t < 61; ++t)   STEP(1,0,0,t);
  for (int t = 61; t < 63; ++t)  STEP(1,0,1,t);
                                 STEP(1,1,1,63);
  for (int t = 64; t < 125; ++t) STEP(0,1,1,t);
  for (int t = 125; t < 127; ++t)STEP(0,1,0,t);
  {                              // t = 127: final LN -> f32 rows for projection
    if (isG) PHASE2();
    bar_lgkm();
    if (!isG) {
      LN2();
      f32x4 oe = {hve0, hve1, hve2, hve3};
      *(f32x4*)&hfin[re][4*l] = oe;
      f32x4 oo = {hvo0, hvo1, hvo2, hvo3};
      *(f32x4*)&hfin[ro][4*l] = oo;
    }
  }

  __syncthreads();
  // final projection: out = h @ W_out + b_out  ([16,256]@[256,10] per block)
  if (tid < ROWS * 10) {
    int r = tid / 10, c = tid % 10;
    float acc = bo[c];
    for (int k = 0; k < H; ++k) acc += hfin[r][k] * Wo[k*10 + c];
    out[((size_t)(r0 + r))*10 + c] = acc;
  }
}

extern "C" void kernel_launch(void* const* d_in, const int* in_sizes, int n_in,
                              void* d_out, int out_size, void* d_ws, size_t ws_size,
                              hipStream_t stream) {
  const float* x   = (const float*)d_in[0];
  const float* We  = (const float*)d_in[1];
  const float* be  = (const float*)d_in[2];
  const float* Wu  = (const float*)d_in[3];
  const float* bu  = (const float*)d_in[4];
  const float* gm  = (const float*)d_in[5];
  const float* bt  = (const float*)d_in[6];
  const float* Wo  = (const float*)d_in[7];
  const float* bo  = (const float*)d_in[8];
  const float* cst = (const float*)d_in[9];
  float* out = (float*)d_out;

  size_t need = (size_t)64 * BT * H * sizeof(unsigned short); // 128 MB history ring
  int use_hist = (ws_size >= need) ? 1 : 0;

  hipLaunchKernelGGL(wp_kernel, dim3(NBLK), dim3(NTH), 0, stream,
                     x, We, be, Wu, bu, gm, bt, Wo, bo, cst,
                     (unsigned short*)d_ws, out, use_hist);
}

// Round 9
// 146.416 us; speedup vs baseline: 1.5523x; 1.5523x over previous
//
#include <hip/hip_runtime.h>
#include <hip/hip_bf16.h>
#include <hip/hip_fp16.h>
#include <stdint.h>

#define H 256
#define BT 4096
#define TS 128
#define ROWS 16
#define NBLK 256   // BT/ROWS, 1 block per CU
#define NTH 1024   // 16 waves, 4/SIMD, all waves active in both phases (r8 lesson)
#define LD 260     // emb row (floats)
#define LDP 264    // hp row (u32, 2-row packed f16)

typedef __attribute__((ext_vector_type(8))) _Float16 f16x8;
typedef __attribute__((ext_vector_type(4))) float f32x4;

__device__ __forceinline__ float exp2_fast(float x){ float r; asm("v_exp_f32 %0, %1" : "=v"(r) : "v"(x)); return r; }
__device__ __forceinline__ float rcp_fast(float x){ float r; asm("v_rcp_f32 %0, %1" : "=v"(r) : "v"(x)); return r; }
__device__ __forceinline__ float rsq_fast(float x){ float r; asm("v_rsq_f32 %0, %1" : "=v"(r) : "v"(x)); return r; }
__device__ __forceinline__ float tanh_fast(float x){
  float e = exp2_fast(x * 2.8853900817779268f);
  return 1.0f - 2.0f * rcp_fast(e + 1.0f);
}
__device__ __forceinline__ unsigned pk_f16(float a, float b){
  __half2 h2 = __float22half2_rn(make_float2(a, b));   // a in low 16
  union { __half2 h; unsigned u; } cv; cv.h = h2; return cv.u;
}
__device__ __forceinline__ float f16_lo(unsigned v){   // cvt low 16 f16->f32
  float r; asm("v_cvt_f32_f16 %0, %1" : "=v"(r) : "v"(v)); return r;
}
__device__ __forceinline__ unsigned pk_bf16(float a, float b){
  __hip_bfloat162 h2 = __float22bfloat162_rn(make_float2(a, b));
  union { __hip_bfloat162 h; unsigned u; } cv; cv.h = h2; return cv.u;
}
// barrier w/o vmcnt drain: cross-wave deps are LDS-only; hist ld/st same-wave, 61+ steps apart
__device__ __forceinline__ void bar_lgkm(){ asm volatile("s_waitcnt lgkmcnt(0)\n\ts_barrier" ::: "memory"); }

template<int CTRL>
__device__ __forceinline__ float dpp_add(float x){
  int y = __builtin_amdgcn_update_dpp(0, __float_as_int(x), CTRL, 0xf, 0xf, false);
  return x + __int_as_float(y);
}
#define ROR1 0x121
#define ROR2 0x122
#define ROR4 0x124
#define ROR8 0x128
#define BC15 0x142
#define BC31 0x143
__device__ __forceinline__ float lane_f(float v, int n){
  return __int_as_float(__builtin_amdgcn_readlane(__float_as_int(v), n));
}

__global__ __launch_bounds__(NTH, 4) void wp_kernel(
    const float* __restrict__ x, const float* __restrict__ We, const float* __restrict__ be,
    const float* __restrict__ Wu, const float* __restrict__ bu, const float* __restrict__ gm,
    const float* __restrict__ bt, const float* __restrict__ Wo, const float* __restrict__ bo,
    const float* __restrict__ cst, unsigned short* __restrict__ hist, float* __restrict__ out,
    int use_hist)
{
  __shared__ __align__(16) float emb[10][LD];
  // h-pre-LN, f16 2-row packed: hp[rp][c] = (h[2rp][c] lo16, h[2rp+1][c] hi16)
  __shared__ __align__(16) unsigned hp[8][LDP];
  __shared__ __align__(16) float hfin[ROWS][LDP];   // final f32 h (t=127 only)
  // A frags (f16): element k=32kc+8fo'+4e'+j of row r in plane kc, physical row
  // (r+16fo')^kc^(2fo'). b128 reads + b64 writes conflict-free (HW-verified r4-r7: 0 conflicts)
  __shared__ __align__(16) unsigned short afrag[8][64][8];

  const int tid = threadIdx.x;
  const int r0 = blockIdx.x * ROWS;
  const int w  = tid >> 6;        // wave 0..15: N-cols [16w,16w+16) phase2; row w phase3
  const int l  = tid & 63;
  const int fr = l & 15;
  const int fo = l >> 4;
  const int c0 = 16*w + fr;       // phase2 D column
  const int rp = w >> 1;          // phase3 rowpair
  const int sh = (w & 1) << 4;    // phase3 sub-row shift within packed u32

  float cs;
  { float c = cst[0]; cs = rcp_fast(1.0f + exp2_fast(-c * 1.4426950408889634f)); }

  // x sequence of this wave's row, packed 4 bytes/u32 into ONE VGPR (lane l<32 holds
  // word l = t in [4l,4l+4)); per-step xv extracted via readlane -> SGPR (no LDS).
  unsigned xw = 0;
  if (l < 32) {
    const float* xp = x + (size_t)(r0 + w)*TS + 4*l;
    unsigned b0 = (unsigned)(int)(xp[0] + 0.5f);
    unsigned b1 = (unsigned)(int)(xp[1] + 0.5f);
    unsigned b2 = (unsigned)(int)(xp[2] + 0.5f);
    unsigned b3 = (unsigned)(int)(xp[3] + 0.5f);
    xw = b0 | (b1 << 8) | (b2 << 16) | (b3 << 24);
  }

  for (int i = tid; i < 10*H; i += NTH) {
    int v = i >> 8, k = i & 255;
    emb[v][k] = tanh_fast((float)v * We[k] + be[k]);
  }

  // W_update f16 frags (32 regs): single-MFMA path (f16 precision, r7-verified)
  f16x8 wf[8];
  #pragma unroll
  for (int kc = 0; kc < 8; ++kc) {
    #pragma unroll
    for (int i = 0; i < 8; ++i) {
      int kg = 32*kc + 8*fo + i;
      wf[kc][i] = (_Float16)Wu[(size_t)kg*H + c0];   // RNE f32->f16
    }
  }
  const float bval = bu[c0];
  f32x4 g4 = *(const f32x4*)(gm + 4*l);
  f32x4 b4 = *(const f32x4*)(bt + 4*l);

  // per-thread-constant addresses (loop-invariant)
  const int XR = l ^ (2*fo);                    // phase2 afrag read row base (^kc per plane)
  const unsigned short* const abase = &afrag[0][0][0];
  // hoisted afrag read element-offsets: plane kc at kc*512, row (XR^kc), 8 halfwords
  int ao[8];
  #pragma unroll
  for (int kc = 0; kc < 8; ++kc) ao[kc] = kc*512 + (XR ^ kc)*8;
  const int wkc = l >> 3, wfo = (l >> 1) & 3, we = l & 1;
  unsigned short* const aw = &afrag[wkc][(w + 16*wfo) ^ wkc ^ (2*wfo)][4*we];
  const unsigned* const hpr = &hp[rp][4*l];
  const size_t histLane = (size_t)(r0 + w)*H + 4*l;
  __syncthreads();

  // prologue: A-frags for t=0 (h=0, no ctx)
  {
    int xv = __builtin_amdgcn_readlane(xw, 0) & 0xff;
    f32x4 e4 = *(const f32x4*)&emb[xv][4*l];
    uint2 p = { pk_f16(e4[0], e4[1]), pk_f16(e4[2], e4[3]) };
    *(uint2*)aw = p;
  }
  __syncthreads();

  uint2 cP = {0,0}, cQ = {0,0};

// phase 2: h_pre = tanh(A @ Wu + bu); bias pre-seeded in acc; f16 2-row-packed store
#define PHASE2() do { \
    f32x4 acc = {bval, bval, bval, bval}; \
    _Pragma("unroll") \
    for (int kc = 0; kc < 8; ++kc) { \
      f16x8 af = *(const f16x8*)(abase + ao[kc]); \
      acc = __builtin_amdgcn_mfma_f32_16x16x32_f16(af, wf[kc], acc, 0, 0, 0); \
    } \
    hp[2*fo  ][c0] = pk_f16(tanh_fast(acc[0]), tanh_fast(acc[1])); \
    hp[2*fo+1][c0] = pk_f16(tanh_fast(acc[2]), tanh_fast(acc[3])); \
  } while(0)

// LN stats + normalized values; h from packed-f16 hp (stats self-consistent on rounded h)
#define LN_STATS_HV() \
    uint4 qv = *(const uint4*)hpr; \
    float h0 = f16_lo(qv.x >> sh); \
    float h1 = f16_lo(qv.y >> sh); \
    float h2 = f16_lo(qv.z >> sh); \
    float h3 = f16_lo(qv.w >> sh); \
    float s1 = (h0+h1) + (h2+h3); \
    float s2 = h0*h0; \
    s2 = fmaf(h1,h1,s2); s2 = fmaf(h2,h2,s2); s2 = fmaf(h3,h3,s2); \
    s1 = dpp_add<ROR1>(s1); s1 = dpp_add<ROR2>(s1); s1 = dpp_add<ROR4>(s1); s1 = dpp_add<ROR8>(s1); \
    s2 = dpp_add<ROR1>(s2); s2 = dpp_add<ROR2>(s2); s2 = dpp_add<ROR4>(s2); s2 = dpp_add<ROR8>(s2); \
    s1 = dpp_add<BC15>(s1); s1 = dpp_add<BC31>(s1); \
    s2 = dpp_add<BC15>(s2); s2 = dpp_add<BC31>(s2); \
    float S1 = lane_f(s1, 63); \
    float S2 = lane_f(s2, 63); \
    float mu  = S1 * 0.00390625f; \
    float var = S2 * 0.00390625f - mu*mu; \
    float rs  = rsq_fast(var + 1e-5f); \
    float hv0 = fmaf(h0-mu, rs*g4[0], b4[0]); \
    float hv1 = fmaf(h1-mu, rs*g4[1], b4[1]); \
    float hv2 = fmaf(h2-mu, rs*g4[2], b4[2]); \
    float hv3 = fmaf(h3-mu, rs*g4[3], b4[3]);

#define PHASE3(HW, CUSE, CLOAD, tt) do { \
    unsigned xwv = (unsigned)__builtin_amdgcn_readlane(xw, ((tt)+1) >> 2); \
    int xv = (xwv >> (8*(((tt)+1) & 3))) & 0xff; \
    f32x4 e4 = *(const f32x4*)&emb[xv][4*l]; \
    LN_STATS_HV(); \
    float a0, a1, a2, a3; \
    if ((CUSE) && use_hist) { \
      a0 = fmaf(cs, __uint_as_float(cP.x << 16),         e4[0] + hv0); \
      a1 = fmaf(cs, __uint_as_float(cP.x & 0xffff0000u), e4[1] + hv1); \
      a2 = fmaf(cs, __uint_as_float(cP.y << 16),         e4[2] + hv2); \
      a3 = fmaf(cs, __uint_as_float(cP.y & 0xffff0000u), e4[3] + hv3); \
    } else { \
      a0 = e4[0] + hv0; a1 = e4[1] + hv1; a2 = e4[2] + hv2; a3 = e4[3] + hv3; \
    } \
    uint2 pkk = { pk_f16(a0,a1), pk_f16(a2,a3) }; \
    *(uint2*)aw = pkk; \
    if ((HW) && use_hist) { \
      uint2 hb = { pk_bf16(hv0,hv1), pk_bf16(hv2,hv3) }; \
      *(uint2*)(hist + (size_t)(tt)*(BT*H) + histLane) = hb; \
    } \
    if ((CUSE) || (CLOAD)) { cP = cQ; } \
    if ((CLOAD) && use_hist) \
      cQ = *(const uint2*)(hist + (size_t)((tt)-61)*(BT*H) + histLane); \
  } while(0)

  // segmented t-loop: all step-uniform branches resolved at compile time per segment
  for (int t = 0; t < 61; ++t)  { PHASE2(); bar_lgkm(); PHASE3(1,0,0,t); bar_lgkm(); }
  for (int t = 61; t < 63; ++t) { PHASE2(); bar_lgkm(); PHASE3(1,0,1,t); bar_lgkm(); }
  {                               PHASE2(); bar_lgkm(); PHASE3(1,1,1,63); bar_lgkm(); }
  for (int t = 64; t < 125; ++t){ PHASE2(); bar_lgkm(); PHASE3(0,1,1,t); bar_lgkm(); }
  for (int t = 125; t < 127; ++t){PHASE2(); bar_lgkm(); PHASE3(0,1,0,t); bar_lgkm(); }
  {                               // t = 127: final LN -> f32 row for projection
    PHASE2(); bar_lgkm();
    LN_STATS_HV();
    f32x4 o = {hv0, hv1, hv2, hv3};
    *(f32x4*)&hfin[w][4*l] = o;
  }

  __syncthreads();
  // final projection: out = h @ W_out + b_out  ([16,256]@[256,10] per block)
  if (tid < ROWS * 10) {
    int r = tid / 10, c = tid % 10;
    float acc = bo[c];
    for (int k = 0; k < H; ++k) acc += hfin[r][k] * Wo[k*10 + c];
    out[((size_t)(r0 + r))*10 + c] = acc;
  }
}

extern "C" void kernel_launch(void* const* d_in, const int* in_sizes, int n_in,
                              void* d_out, int out_size, void* d_ws, size_t ws_size,
                              hipStream_t stream) {
  const float* x   = (const float*)d_in[0];
  const float* We  = (const float*)d_in[1];
  const float* be  = (const float*)d_in[2];
  const float* Wu  = (const float*)d_in[3];
  const float* bu  = (const float*)d_in[4];
  const float* gm  = (const float*)d_in[5];
  const float* bt  = (const float*)d_in[6];
  const float* Wo  = (const float*)d_in[7];
  const float* bo  = (const float*)d_in[8];
  const float* cst = (const float*)d_in[9];
  float* out = (float*)d_out;

  size_t need = (size_t)64 * BT * H * sizeof(unsigned short); // 128 MB history ring
  int use_hist = (ws_size >= need) ? 1 : 0;

  hipLaunchKernelGGL(wp_kernel, dim3(NBLK), dim3(NTH), 0, stream,
                     x, We, be, Wu, bu, gm, bt, Wo, bo, cst,
                     (unsigned short*)d_ws, out, use_hist);
}